// Round 9
// baseline (208.534 us; speedup 1.0000x reference)
//
#include <hip/hip_runtime.h>
#include <hip/hip_bf16.h>
#include <math.h>

#define N_NODES 50000
#define N_EDGES 400000
#define IN_DIM 256
#define OUT_DIM 64
#define HEADS 2
#define ATTN_HIDDEN 64
#define ALPHA_SLOPE 0.2f
#define TEMP 0.55f
#define NHF 128   // HEADS*OUT_DIM
#define ZDIM 384  // Wh(128) | Us(128) | Ud(128)

typedef __bf16 bf16x8 __attribute__((ext_vector_type(8)));
typedef float f32x4 __attribute__((ext_vector_type(4)));

__device__ __forceinline__ ushort f2bf(float f) {
    unsigned u = __float_as_uint(f);
    u = (u + 0x7fffu + ((u >> 16) & 1u)) >> 16;
    return (ushort)u;
}
__device__ __forceinline__ unsigned pack2(float a, float b) {
    return (unsigned)f2bf(a) | ((unsigned)f2bf(b) << 16);
}
__device__ __forceinline__ float bfl(unsigned u) { return __uint_as_float(u << 16); }
__device__ __forceinline__ float bfh(unsigned u) { return __uint_as_float(u & 0xffff0000u); }

// ---------------------------------------------------------------------------
// K1: build Wctf (combined weights, MFMA B-fragment order) + seg[] (segment
// starts) in one launch. Fragment position for (n,k): c=n>>4, r16=n&15,
// kc=k>>5, q=(k>>3)&3, j=k&7 -> pos = ((c*8+kc)*64 + q*16 + r16)*8 + j.
// ---------------------------------------------------------------------------
__global__ __launch_bounds__(256) void k_combine(const float* __restrict__ W,
                                                 const float* __restrict__ Wa,
                                                 ushort* __restrict__ Wctf,
                                                 const int* __restrict__ dst,
                                                 int* __restrict__ seg) {
    __shared__ float col[64];
    const int b = blockIdx.x;
    const int t = threadIdx.x;
    if (b >= ZDIM) {   // segstart path
        int n = (b - ZDIM) * 256 + t;
        if (n > N_NODES) return;
        int lo = 0, hi = N_EDGES;
        while (lo < hi) {
            int mid = (lo + hi) >> 1;
            if (dst[mid] < n) lo = mid + 1; else hi = mid;
        }
        seg[n] = lo;
        return;
    }
    const int n = b;      // output column 0..383
    const int k = t;      // input dim 0..255
    const int c = n >> 4, r16 = n & 15;
    const int kc = k >> 5, q = (k >> 3) & 3, j = k & 7;
    const size_t pos = (size_t)(((c * 8 + kc) * 64 + q * 16 + r16)) * 8 + j;

    float val;
    if (n < 128) {
        val = W[(size_t)k * NHF + n];
    } else {
        const int part = (n - 128) >> 7;       // 0 = src-half, 1 = dst-half
        const int idx = (n - 128) & 127;
        const int h = idx >> 6;
        const int cc = idx & 63;
        const int fb = part ? 64 : 0;
        if (t < 64) col[t] = Wa[(size_t)h * 8192 + (size_t)(fb + t) * 64 + cc];
        __syncthreads();
        const float* wr = W + (size_t)k * NHF + h * 64;
        float acc = 0.f;
#pragma unroll
        for (int f = 0; f < 64; f++) acc += wr[f] * col[f];
        val = acc;
    }
    Wctf[pos] = f2bf(val);
}

// ---------------------------------------------------------------------------
// K2: Z[50000,384] = x @ Wcomb. No LDS, no barriers. Wave = 32 rows x 192
// cols (12 c-tiles); 4 waves/block. Software-pipelined 1-deep: each B
// register b[c] is reloaded for kc+1 immediately after its two MFMAs consume
// it (WAR-pinned interleaved MFMA<->load stream, ~16 loads in flight); A is
// packed then immediately reloaded for kc+1. No extra register cost.
// A frag: A[m=lane&15][k=(lane>>4)*8+j]; D: row=(lane>>4)*4+rr, col=lane&15.
// ---------------------------------------------------------------------------
__global__ __launch_bounds__(256, 3) void k_gemm(const float* __restrict__ x,
                                                 const ushort* __restrict__ Wctf,
                                                 ushort* __restrict__ Zb) {
    const int t = threadIdx.x;
    const int w = t >> 6, lane = t & 63;
    const int q = lane >> 4, r16 = lane & 15;
    const int chalf = (w & 1) * 12;                 // c-tile base (0 or 12)
    const int rowbase = blockIdx.x * 64 + (w >> 1) * 32;
    if (rowbase >= N_NODES) return;

    int rA0 = rowbase + r16;
    int rA1 = rowbase + 16 + r16;
    rA0 = rA0 < N_NODES ? rA0 : N_NODES - 1;
    rA1 = rA1 < N_NODES ? rA1 : N_NODES - 1;
    const float* xp0 = x + (size_t)rA0 * IN_DIM + q * 8;
    const float* xp1 = x + (size_t)rA1 * IN_DIM + q * 8;
    const ushort* bp = Wctf + chalf * 4096 + lane * 8;

    f32x4 acc[2][12];
#pragma unroll
    for (int c = 0; c < 12; c++) { acc[0][c] = (f32x4){0.f,0.f,0.f,0.f}; acc[1][c] = (f32x4){0.f,0.f,0.f,0.f}; }

    // prologue: loads for kc=0
    float4 a00 = *(const float4*)(xp0);
    float4 a01 = *(const float4*)(xp0 + 4);
    float4 a10 = *(const float4*)(xp1);
    float4 a11 = *(const float4*)(xp1 + 4);
    uint4 b[12];
#pragma unroll
    for (int c = 0; c < 12; c++) b[c] = *(const uint4*)(bp + c * 4096);

#pragma unroll 1
    for (int kc = 0; kc < 8; kc++) {
        const int kn = ((kc + 1) & 7) * 32;        // next chunk (wraps: dead loads on last iter)
        // pack current A, then immediately reload A for kc+1 (WAR-pinned)
        uint4 p0, p1;
        p0.x = pack2(a00.x, a00.y); p0.y = pack2(a00.z, a00.w);
        p0.z = pack2(a01.x, a01.y); p0.w = pack2(a01.z, a01.w);
        p1.x = pack2(a10.x, a10.y); p1.y = pack2(a10.z, a10.w);
        p1.z = pack2(a11.x, a11.y); p1.w = pack2(a11.z, a11.w);
        const bf16x8 af0 = *(const bf16x8*)&p0;
        const bf16x8 af1 = *(const bf16x8*)&p1;
        a00 = *(const float4*)(xp0 + kn);
        a01 = *(const float4*)(xp0 + kn + 4);
        a10 = *(const float4*)(xp1 + kn);
        a11 = *(const float4*)(xp1 + kn + 4);
        // interleaved MFMA <-> B-reload stream
        const ushort* bkn = bp + kn * 16;          // kn*16 ushorts == ((kc+1)&7)*512
#pragma unroll
        for (int c = 0; c < 12; c++) {
            const bf16x8 bf = *(const bf16x8*)&b[c];
            acc[0][c] = __builtin_amdgcn_mfma_f32_16x16x32_bf16(af0, bf, acc[0][c], 0, 0, 0);
            acc[1][c] = __builtin_amdgcn_mfma_f32_16x16x32_bf16(af1, bf, acc[1][c], 0, 0, 0);
            b[c] = *(const uint4*)(bkn + c * 4096);
        }
    }
#pragma unroll
    for (int mt = 0; mt < 2; mt++)
#pragma unroll
        for (int c = 0; c < 12; c++)
#pragma unroll
            for (int rr = 0; rr < 4; rr++) {
                const int row = rowbase + mt * 16 + q * 4 + rr;
                if (row < N_NODES)
                    Zb[(size_t)row * ZDIM + (chalf + c) * 16 + r16] = f2bf(acc[mt][c][rr]);
            }
}

// ---------------------------------------------------------------------------
// K3: fused logits + online segment-softmax + weighted accumulate.
// 16 lanes per node, 4 nodes per wave, 16 nodes per block. DUAL independent
// online-softmax chains (even/odd edges) per node, each 1-deep prefetched
// (4 gathers in flight), merged exactly at the end.
// ---------------------------------------------------------------------------
__global__ __launch_bounds__(256) void k_fused(const ushort* __restrict__ Zb,
                                               const float* __restrict__ avec,
                                               const int* __restrict__ src,
                                               const int* __restrict__ seg,
                                               float* __restrict__ out) {
    const int lane = threadIdx.x & 63;
    const int wv = threadIdx.x >> 6;
    const int g = lane >> 4, l16 = lane & 15;
    const int n = blockIdx.x * 16 + wv * 4 + g;
    if (n >= N_NODES) return;
    const int choff = 8 * l16;

    const float4 af0 = *(const float4*)(avec + choff);
    const float4 af1 = *(const float4*)(avec + choff + 4);
    const float a[8] = {af0.x, af0.y, af0.z, af0.w, af1.x, af1.y, af1.z, af1.w};

    const uint4 udv = *(const uint4*)(Zb + (size_t)n * ZDIM + 256 + choff);
    const float ud[8] = {bfl(udv.x), bfh(udv.x), bfl(udv.y), bfh(udv.y),
                         bfl(udv.z), bfh(udv.z), bfl(udv.w), bfh(udv.w)};

    const int e0 = seg[n], e1 = seg[n + 1];
    const int cnt = e1 - e0;

    float m0 = -INFINITY, l0 = 0.f, m1 = -INFINITY, l1 = 0.f;
    float ac0[8] = {0,0,0,0,0,0,0,0}, ac1[8] = {0,0,0,0,0,0,0,0};

    auto step = [&](float& m, float& l, float* ac, const uint4 cus, const uint4 cwh) {
        float p;
        {
            float v0, v1, s0, s1;
            v0 = bfl(cus.x) + ud[0]; v1 = bfh(cus.x) + ud[1];
            s0 = fmaxf(v0, ALPHA_SLOPE * v0); s1 = fmaxf(v1, ALPHA_SLOPE * v1);
            p = s0 * a[0] + s1 * a[1];
            v0 = bfl(cus.y) + ud[2]; v1 = bfh(cus.y) + ud[3];
            s0 = fmaxf(v0, ALPHA_SLOPE * v0); s1 = fmaxf(v1, ALPHA_SLOPE * v1);
            p += s0 * a[2] + s1 * a[3];
            v0 = bfl(cus.z) + ud[4]; v1 = bfh(cus.z) + ud[5];
            s0 = fmaxf(v0, ALPHA_SLOPE * v0); s1 = fmaxf(v1, ALPHA_SLOPE * v1);
            p += s0 * a[4] + s1 * a[5];
            v0 = bfl(cus.w) + ud[6]; v1 = bfh(cus.w) + ud[7];
            s0 = fmaxf(v0, ALPHA_SLOPE * v0); s1 = fmaxf(v1, ALPHA_SLOPE * v1);
            p += s0 * a[6] + s1 * a[7];
        }
        p += __shfl_xor(p, 1, 64);
        p += __shfl_xor(p, 2, 64);
        p += __shfl_xor(p, 4, 64);        // lanes 0-7: head0 logit, 8-15: head1
        const float logit = p * (1.0f / TEMP);
        const float nm = fmaxf(m, logit);
        const float sc = __expf(m - nm);       // first iter: exp(-inf)=0
        const float wgt = __expf(logit - nm);
        l = l * sc + wgt;
        ac[0] = ac[0] * sc + wgt * bfl(cwh.x);
        ac[1] = ac[1] * sc + wgt * bfh(cwh.x);
        ac[2] = ac[2] * sc + wgt * bfl(cwh.y);
        ac[3] = ac[3] * sc + wgt * bfh(cwh.y);
        ac[4] = ac[4] * sc + wgt * bfl(cwh.z);
        ac[5] = ac[5] * sc + wgt * bfh(cwh.z);
        ac[6] = ac[6] * sc + wgt * bfl(cwh.w);
        ac[7] = ac[7] * sc + wgt * bfh(cwh.w);
        m = nm;
    };

    uint4 us0 = make_uint4(0,0,0,0), wh0 = us0, us1 = us0, wh1 = us0;
    if (cnt > 0) {
        const int s = src[e0];
        us0 = *(const uint4*)(Zb + (size_t)s * ZDIM + 128 + choff);
        wh0 = *(const uint4*)(Zb + (size_t)s * ZDIM + choff);
    }
    if (cnt > 1) {
        const int s = src[e0 + 1];
        us1 = *(const uint4*)(Zb + (size_t)s * ZDIM + 128 + choff);
        wh1 = *(const uint4*)(Zb + (size_t)s * ZDIM + choff);
    }
    int i = 0;
    while (i + 1 < cnt) {
        const uint4 cu0 = us0, cw0 = wh0, cu1 = us1, cw1 = wh1;
        if (i + 2 < cnt) {
            const int s = src[e0 + i + 2];
            us0 = *(const uint4*)(Zb + (size_t)s * ZDIM + 128 + choff);
            wh0 = *(const uint4*)(Zb + (size_t)s * ZDIM + choff);
        }
        if (i + 3 < cnt) {
            const int s = src[e0 + i + 3];
            us1 = *(const uint4*)(Zb + (size_t)s * ZDIM + 128 + choff);
            wh1 = *(const uint4*)(Zb + (size_t)s * ZDIM + choff);
        }
        step(m0, l0, ac0, cu0, cw0);      // two independent chains -> 2x ILP
        step(m1, l1, ac1, cu1, cw1);
        i += 2;
    }
    if (i < cnt) step(m0, l0, ac0, us0, wh0);

    // exact merge of the two online-softmax states (guards for empty chains)
    const float mm = fmaxf(m0, m1);
    const float s0 = (m0 != -INFINITY) ? __expf(m0 - mm) : 0.f;
    const float s1 = (m1 != -INFINITY) ? __expf(m1 - mm) : 0.f;
    const float lt = l0 * s0 + l1 * s1;
    const float inv = 0.5f / (lt + 1e-9f);     // ref 1/(sum+1e-9) + head-mean
    float acc[8];
#pragma unroll
    for (int j = 0; j < 8; j++) {
        const float v = (ac0[j] * s0 + ac1[j] * s1) * inv;
        acc[j] = v + __shfl_xor(v, 8, 64);     // head0[c] + head1[c]
    }
    if (l16 < 8) {
        float4 o0 = make_float4(acc[0], acc[1], acc[2], acc[3]);
        float4 o1 = make_float4(acc[4], acc[5], acc[6], acc[7]);
        float* op = out + (size_t)n * 64 + choff;
        *(float4*)op = o0;
        *(float4*)(op + 4) = o1;
    }
}

// ---------------------------------------------------------------------------
extern "C" void kernel_launch(void* const* d_in, const int* in_sizes, int n_in,
                              void* d_out, int out_size, void* d_ws, size_t ws_size,
                              hipStream_t stream) {
    const float* x    = (const float*)d_in[0];
    const float* W    = (const float*)d_in[1];
    const float* Wa   = (const float*)d_in[2];
    const float* avec = (const float*)d_in[3];
    const int*   src  = (const int*)d_in[4];
    const int*   dst  = (const int*)d_in[5];
    float* out = (float*)d_out;

    ushort* Zb   = (ushort*)d_ws;                      // 19,200,000 bf16 = 38.4 MB
    ushort* Wctf = Zb + 19200000;                      // 98,304 bf16 (fragment order)
    int*    seg  = (int*)((char*)d_ws + 38596608);     // 50,001 ints

    const int seg_blocks = (N_NODES + 1 + 255) / 256;  // 196
    k_combine <<<ZDIM + seg_blocks, 256, 0, stream>>>(W, Wa, Wctf, dst, seg);
    k_gemm    <<<(N_NODES + 63) / 64, 256, 0, stream>>>(x, Wctf, Zb);
    k_fused   <<<(N_NODES + 15) / 16, 256, 0, stream>>>(Zb, avec, src, seg, out);
}

// Round 10
// 167.676 us; speedup vs baseline: 1.2437x; 1.2437x over previous
//
#include <hip/hip_runtime.h>
#include <hip/hip_bf16.h>
#include <math.h>

#define N_NODES 50000
#define N_EDGES 400000
#define IN_DIM 256
#define OUT_DIM 64
#define HEADS 2
#define ATTN_HIDDEN 64
#define ALPHA_SLOPE 0.2f
#define TEMP 0.55f
#define NHF 128   // HEADS*OUT_DIM
#define ZDIM 384  // Wh(128) | Us(128) | Ud(128)

typedef __bf16 bf16x8 __attribute__((ext_vector_type(8)));
typedef float f32x4 __attribute__((ext_vector_type(4)));

__device__ __forceinline__ ushort f2bf(float f) {
    unsigned u = __float_as_uint(f);
    u = (u + 0x7fffu + ((u >> 16) & 1u)) >> 16;
    return (ushort)u;
}
__device__ __forceinline__ unsigned pack2(float a, float b) {
    return (unsigned)f2bf(a) | ((unsigned)f2bf(b) << 16);
}
__device__ __forceinline__ float bfl(unsigned u) { return __uint_as_float(u << 16); }
__device__ __forceinline__ float bfh(unsigned u) { return __uint_as_float(u & 0xffff0000u); }

// ---------------------------------------------------------------------------
// K1: build Wctf (combined weights, MFMA B-fragment order) + seg[] (segment
// starts) in one launch. Fragment position for (n,k): c=n>>4, r16=n&15,
// kc=k>>5, q=(k>>3)&3, j=k&7 -> pos = ((c*8+kc)*64 + q*16 + r16)*8 + j.
// Note: each 8-c-tile group (128 cols) is a contiguous 64 KB slab — k_gemm
// stages one slab to LDS wholesale.
// ---------------------------------------------------------------------------
__global__ __launch_bounds__(256) void k_combine(const float* __restrict__ W,
                                                 const float* __restrict__ Wa,
                                                 ushort* __restrict__ Wctf,
                                                 const int* __restrict__ dst,
                                                 int* __restrict__ seg) {
    __shared__ float col[64];
    const int b = blockIdx.x;
    const int t = threadIdx.x;
    if (b >= ZDIM) {   // segstart path
        int n = (b - ZDIM) * 256 + t;
        if (n > N_NODES) return;
        int lo = 0, hi = N_EDGES;
        while (lo < hi) {
            int mid = (lo + hi) >> 1;
            if (dst[mid] < n) lo = mid + 1; else hi = mid;
        }
        seg[n] = lo;
        return;
    }
    const int n = b;      // output column 0..383
    const int k = t;      // input dim 0..255
    const int c = n >> 4, r16 = n & 15;
    const int kc = k >> 5, q = (k >> 3) & 3, j = k & 7;
    const size_t pos = (size_t)(((c * 8 + kc) * 64 + q * 16 + r16)) * 8 + j;

    float val;
    if (n < 128) {
        val = W[(size_t)k * NHF + n];
    } else {
        const int part = (n - 128) >> 7;       // 0 = src-half, 1 = dst-half
        const int idx = (n - 128) & 127;
        const int h = idx >> 6;
        const int cc = idx & 63;
        const int fb = part ? 64 : 0;
        if (t < 64) col[t] = Wa[(size_t)h * 8192 + (size_t)(fb + t) * 64 + cc];
        __syncthreads();
        const float* wr = W + (size_t)k * NHF + h * 64;
        float acc = 0.f;
#pragma unroll
        for (int f = 0; f < 64; f++) acc += wr[f] * col[f];
        val = acc;
    }
    Wctf[pos] = f2bf(val);
}

// ---------------------------------------------------------------------------
// K2: Z[50000,384] = x @ Wcomb. Grid (3 col-splits, 391 row-tiles).
// Block: 256 thr = 4 waves x 32 rows, 128 cols (8 c-tiles).
// B: the split's contiguous 64 KB fragment-order slab staged to LDS ONCE
// (coalesced uint4 -> lane-linear ds_write_b128), one barrier, then an
// 8-iter K-loop with NO barriers: 4 A-loads (1-deep prefetch) + 8
// conflict-free ds_read_b128 + 16 MFMAs per iter. x re-reads across the 3
// splits are L3-resident (same-row splits adjacent in dispatch order).
// A frag: A[m=lane&15][k=(lane>>4)*8+j]; D: row=(lane>>4)*4+rr, col=lane&15.
// ---------------------------------------------------------------------------
__global__ __launch_bounds__(256, 2) void k_gemm(const float* __restrict__ x,
                                                 const ushort* __restrict__ Wctf,
                                                 ushort* __restrict__ Zb) {
    __shared__ __align__(16) ushort Bs[32768];   // 64 KB
    const int t = threadIdx.x;
    const int w = t >> 6, lane = t & 63;
    const int q = lane >> 4, r16 = lane & 15;
    const int cbase = blockIdx.x * 8;                 // c-tile base (0/8/16)
    const int rowbase = blockIdx.y * 128 + w * 32;    // wave's 32 rows

    // ---- stage B slab (contiguous 64 KB) into LDS, once
    {
        const uint4* gs = (const uint4*)(Wctf + (size_t)blockIdx.x * 32768);
        uint4* ls = (uint4*)Bs;
#pragma unroll
        for (int i = 0; i < 16; i++) ls[i * 256 + t] = gs[i * 256 + t];
    }

    int rA0 = rowbase + r16;
    int rA1 = rowbase + 16 + r16;
    rA0 = rA0 < N_NODES ? rA0 : N_NODES - 1;
    rA1 = rA1 < N_NODES ? rA1 : N_NODES - 1;
    const float* xp0 = x + (size_t)rA0 * IN_DIM + q * 8;
    const float* xp1 = x + (size_t)rA1 * IN_DIM + q * 8;

    f32x4 acc[2][8];
#pragma unroll
    for (int c = 0; c < 8; c++) {
        acc[0][c] = (f32x4){0.f, 0.f, 0.f, 0.f};
        acc[1][c] = (f32x4){0.f, 0.f, 0.f, 0.f};
    }

    // prologue A loads (kc = 0)
    float4 a00 = *(const float4*)(xp0);
    float4 a01 = *(const float4*)(xp0 + 4);
    float4 a10 = *(const float4*)(xp1);
    float4 a11 = *(const float4*)(xp1 + 4);

    __syncthreads();   // B slab visible; the only barrier in the kernel

#pragma unroll 1
    for (int kc = 0; kc < 8; kc++) {
        uint4 p0, p1;
        p0.x = pack2(a00.x, a00.y); p0.y = pack2(a00.z, a00.w);
        p0.z = pack2(a01.x, a01.y); p0.w = pack2(a01.z, a01.w);
        p1.x = pack2(a10.x, a10.y); p1.y = pack2(a10.z, a10.w);
        p1.z = pack2(a11.x, a11.y); p1.w = pack2(a11.z, a11.w);
        const bf16x8 af0 = *(const bf16x8*)&p0;
        const bf16x8 af1 = *(const bf16x8*)&p1;
        if (kc < 7) {
            const int kn = (kc + 1) * 32;
            a00 = *(const float4*)(xp0 + kn);
            a01 = *(const float4*)(xp0 + kn + 4);
            a10 = *(const float4*)(xp1 + kn);
            a11 = *(const float4*)(xp1 + kn + 4);
        }
#pragma unroll
        for (int c = 0; c < 8; c++) {
            const bf16x8 bf = *(const bf16x8*)&Bs[((c * 8 + kc) * 64 + lane) * 8];
            acc[0][c] = __builtin_amdgcn_mfma_f32_16x16x32_bf16(af0, bf, acc[0][c], 0, 0, 0);
            acc[1][c] = __builtin_amdgcn_mfma_f32_16x16x32_bf16(af1, bf, acc[1][c], 0, 0, 0);
        }
    }
#pragma unroll
    for (int mt = 0; mt < 2; mt++)
#pragma unroll
        for (int c = 0; c < 8; c++)
#pragma unroll
            for (int rr = 0; rr < 4; rr++) {
                const int row = rowbase + mt * 16 + q * 4 + rr;
                if (row < N_NODES)
                    Zb[(size_t)row * ZDIM + (cbase + c) * 16 + r16] = f2bf(acc[mt][c][rr]);
            }
}

// ---------------------------------------------------------------------------
// K3: fused logits + online segment-softmax + weighted accumulate.
// 16 lanes per node, 4 nodes per wave, 16 nodes per block (R5 form — best
// measured). Lane l16 owns channels 8*l16..8*l16+7 (l16<8: head0, else
// head1). Per edge: uint4 gather of Us[src] + Wh[src], 1-deep prefetch;
// 3 xor-shuffles; per-lane online (m,l); head-mean via final xor-8.
// ---------------------------------------------------------------------------
__global__ __launch_bounds__(256) void k_fused(const ushort* __restrict__ Zb,
                                               const float* __restrict__ avec,
                                               const int* __restrict__ src,
                                               const int* __restrict__ seg,
                                               float* __restrict__ out) {
    const int lane = threadIdx.x & 63;
    const int wv = threadIdx.x >> 6;
    const int g = lane >> 4, l16 = lane & 15;
    const int n = blockIdx.x * 16 + wv * 4 + g;
    if (n >= N_NODES) return;
    const int choff = 8 * l16;

    const float4 af0 = *(const float4*)(avec + choff);
    const float4 af1 = *(const float4*)(avec + choff + 4);
    const float a[8] = {af0.x, af0.y, af0.z, af0.w, af1.x, af1.y, af1.z, af1.w};

    const uint4 udv = *(const uint4*)(Zb + (size_t)n * ZDIM + 256 + choff);
    const float ud[8] = {bfl(udv.x), bfh(udv.x), bfl(udv.y), bfh(udv.y),
                         bfl(udv.z), bfh(udv.z), bfl(udv.w), bfh(udv.w)};

    const int e0 = seg[n], e1 = seg[n + 1];
    float m = -INFINITY, l = 0.f;
    float acc[8] = {0.f, 0.f, 0.f, 0.f, 0.f, 0.f, 0.f, 0.f};

    uint4 us = make_uint4(0, 0, 0, 0), wh = us;
    if (e0 < e1) {
        const int s = src[e0];
        us = *(const uint4*)(Zb + (size_t)s * ZDIM + 128 + choff);
        wh = *(const uint4*)(Zb + (size_t)s * ZDIM + choff);
    }
    for (int e = e0; e < e1; e++) {
        const uint4 cus = us, cwh = wh;
        if (e + 1 < e1) {                 // prefetch next edge during reduce
            const int sn = src[e + 1];
            us = *(const uint4*)(Zb + (size_t)sn * ZDIM + 128 + choff);
            wh = *(const uint4*)(Zb + (size_t)sn * ZDIM + choff);
        }
        float p;
        {
            float v0, v1, s0, s1;
            v0 = bfl(cus.x) + ud[0]; v1 = bfh(cus.x) + ud[1];
            s0 = fmaxf(v0, ALPHA_SLOPE * v0); s1 = fmaxf(v1, ALPHA_SLOPE * v1);
            p = s0 * a[0] + s1 * a[1];
            v0 = bfl(cus.y) + ud[2]; v1 = bfh(cus.y) + ud[3];
            s0 = fmaxf(v0, ALPHA_SLOPE * v0); s1 = fmaxf(v1, ALPHA_SLOPE * v1);
            p += s0 * a[2] + s1 * a[3];
            v0 = bfl(cus.z) + ud[4]; v1 = bfh(cus.z) + ud[5];
            s0 = fmaxf(v0, ALPHA_SLOPE * v0); s1 = fmaxf(v1, ALPHA_SLOPE * v1);
            p += s0 * a[4] + s1 * a[5];
            v0 = bfl(cus.w) + ud[6]; v1 = bfh(cus.w) + ud[7];
            s0 = fmaxf(v0, ALPHA_SLOPE * v0); s1 = fmaxf(v1, ALPHA_SLOPE * v1);
            p += s0 * a[6] + s1 * a[7];
        }
        p += __shfl_xor(p, 1, 64);
        p += __shfl_xor(p, 2, 64);
        p += __shfl_xor(p, 4, 64);        // lanes 0-7: head0 logit, 8-15: head1
        const float logit = p * (1.0f / TEMP);
        const float nm = fmaxf(m, logit);
        const float sc = __expf(m - nm);       // first iter: exp(-inf)=0
        const float wgt = __expf(logit - nm);
        l = l * sc + wgt;
        acc[0] = acc[0] * sc + wgt * bfl(cwh.x);
        acc[1] = acc[1] * sc + wgt * bfh(cwh.x);
        acc[2] = acc[2] * sc + wgt * bfl(cwh.y);
        acc[3] = acc[3] * sc + wgt * bfh(cwh.y);
        acc[4] = acc[4] * sc + wgt * bfl(cwh.z);
        acc[5] = acc[5] * sc + wgt * bfh(cwh.z);
        acc[6] = acc[6] * sc + wgt * bfl(cwh.w);
        acc[7] = acc[7] * sc + wgt * bfh(cwh.w);
        m = nm;
    }
    const float inv = 0.5f / (l + 1e-9f);      // ref 1/(sum+1e-9) + head-mean
#pragma unroll
    for (int j = 0; j < 8; j++) {
        const float v = acc[j] * inv;
        acc[j] = v + __shfl_xor(v, 8, 64);     // head0[c] + head1[c]
    }
    if (l16 < 8) {
        float4 o0 = make_float4(acc[0], acc[1], acc[2], acc[3]);
        float4 o1 = make_float4(acc[4], acc[5], acc[6], acc[7]);
        float* op = out + (size_t)n * 64 + choff;
        *(float4*)op = o0;
        *(float4*)(op + 4) = o1;
    }
}

// ---------------------------------------------------------------------------
extern "C" void kernel_launch(void* const* d_in, const int* in_sizes, int n_in,
                              void* d_out, int out_size, void* d_ws, size_t ws_size,
                              hipStream_t stream) {
    const float* x    = (const float*)d_in[0];
    const float* W    = (const float*)d_in[1];
    const float* Wa   = (const float*)d_in[2];
    const float* avec = (const float*)d_in[3];
    const int*   src  = (const int*)d_in[4];
    const int*   dst  = (const int*)d_in[5];
    float* out = (float*)d_out;

    ushort* Zb   = (ushort*)d_ws;                      // 19,200,000 bf16 = 38.4 MB
    ushort* Wctf = Zb + 19200000;                      // 98,304 bf16 (fragment order)
    int*    seg  = (int*)((char*)d_ws + 38596608);     // 50,001 ints

    const int seg_blocks = (N_NODES + 1 + 255) / 256;  // 196
    k_combine <<<ZDIM + seg_blocks, 256, 0, stream>>>(W, Wa, Wctf, dst, seg);
    k_gemm    <<<dim3(3, (N_NODES + 127) / 128), 256, 0, stream>>>(x, Wctf, Zb);
    k_fused   <<<(N_NODES + 15) / 16, 256, 0, stream>>>(Zb, avec, src, seg, out);
}

// Round 11
// 162.508 us; speedup vs baseline: 1.2832x; 1.0318x over previous
//
#include <hip/hip_runtime.h>
#include <hip/hip_bf16.h>
#include <math.h>

#define N_NODES 50000
#define N_EDGES 400000
#define IN_DIM 256
#define OUT_DIM 64
#define HEADS 2
#define ATTN_HIDDEN 64
#define ALPHA_SLOPE 0.2f
#define TEMP 0.55f
#define NHF 128   // HEADS*OUT_DIM
#define ZDIM 384  // Wh(128) | Us(128) | Ud(128)

typedef __bf16 bf16x8 __attribute__((ext_vector_type(8)));
typedef float f32x4 __attribute__((ext_vector_type(4)));

__device__ __forceinline__ ushort f2bf(float f) {
    unsigned u = __float_as_uint(f);
    u = (u + 0x7fffu + ((u >> 16) & 1u)) >> 16;
    return (ushort)u;
}
__device__ __forceinline__ unsigned pack2(float a, float b) {
    return (unsigned)f2bf(a) | ((unsigned)f2bf(b) << 16);
}
__device__ __forceinline__ float bfl(unsigned u) { return __uint_as_float(u << 16); }
__device__ __forceinline__ float bfh(unsigned u) { return __uint_as_float(u & 0xffff0000u); }

// ---------------------------------------------------------------------------
// K1: build Wctf (combined weights, MFMA B-fragment order) + seg[] (segment
// starts) in one launch. Fragment position for (n,k): c=n>>4, r16=n&15,
// kc=k>>5, q=(k>>3)&3, j=k&7 -> pos = ((c*8+kc)*64 + q*16 + r16)*8 + j.
// Each 8-c-tile group (128 cols) is a contiguous 64 KB slab.
// ---------------------------------------------------------------------------
__global__ __launch_bounds__(256) void k_combine(const float* __restrict__ W,
                                                 const float* __restrict__ Wa,
                                                 ushort* __restrict__ Wctf,
                                                 const int* __restrict__ dst,
                                                 int* __restrict__ seg) {
    __shared__ float col[64];
    const int b = blockIdx.x;
    const int t = threadIdx.x;
    if (b >= ZDIM) {   // segstart path
        int n = (b - ZDIM) * 256 + t;
        if (n > N_NODES) return;
        int lo = 0, hi = N_EDGES;
        while (lo < hi) {
            int mid = (lo + hi) >> 1;
            if (dst[mid] < n) lo = mid + 1; else hi = mid;
        }
        seg[n] = lo;
        return;
    }
    const int n = b;      // output column 0..383
    const int k = t;      // input dim 0..255
    const int c = n >> 4, r16 = n & 15;
    const int kc = k >> 5, q = (k >> 3) & 3, j = k & 7;
    const size_t pos = (size_t)(((c * 8 + kc) * 64 + q * 16 + r16)) * 8 + j;

    float val;
    if (n < 128) {
        val = W[(size_t)k * NHF + n];
    } else {
        const int part = (n - 128) >> 7;       // 0 = src-half, 1 = dst-half
        const int idx = (n - 128) & 127;
        const int h = idx >> 6;
        const int cc = idx & 63;
        const int fb = part ? 64 : 0;
        if (t < 64) col[t] = Wa[(size_t)h * 8192 + (size_t)(fb + t) * 64 + cc];
        __syncthreads();
        const float* wr = W + (size_t)k * NHF + h * 64;
        float acc = 0.f;
#pragma unroll
        for (int f = 0; f < 64; f++) acc += wr[f] * col[f];
        val = acc;
    }
    Wctf[pos] = f2bf(val);
}

// ---------------------------------------------------------------------------
// K2: Z[50000,384] = x @ Wcomb. Grid (3 col-splits, 391 row-tiles).
// Block: 4 waves x 32 rows, 128 cols (8 c-tiles).
// B: split's contiguous 64 KB slab staged to LDS once (coalesced uint4 ->
// lane-linear ds_write_b128, conflict-free). A: the wave's ENTIRE A panel
// (2 m-tiles x 8 kc = 16 uint4/lane after bf16 pack) loaded in the prologue
// with all 32 float4 loads in flight. K-loop is then global-free and
// barrier-free: 64 ds_read_b128 + 128 MFMA, fully unrolled, only
// fine-grained lgkmcnt between LDS reads and MFMAs.
// A frag: A[m=lane&15][k=(lane>>4)*8+j]; D: row=(lane>>4)*4+rr, col=lane&15.
// ---------------------------------------------------------------------------
__global__ __launch_bounds__(256, 2) void k_gemm(const float* __restrict__ x,
                                                 const ushort* __restrict__ Wctf,
                                                 ushort* __restrict__ Zb) {
    __shared__ __align__(16) ushort Bs[32768];   // 64 KB
    const int t = threadIdx.x;
    const int w = t >> 6, lane = t & 63;
    const int q = lane >> 4, r16 = lane & 15;
    const int cbase = blockIdx.x * 8;                 // c-tile base (0/8/16)
    const int rowbase = blockIdx.y * 128 + w * 32;    // wave's 32 rows

    // ---- stage B slab (contiguous 64 KB) into LDS, once
    {
        const uint4* gs = (const uint4*)(Wctf + (size_t)blockIdx.x * 32768);
        uint4* ls = (uint4*)Bs;
#pragma unroll
        for (int i = 0; i < 16; i++) ls[i * 256 + t] = gs[i * 256 + t];
    }

    int rA0 = rowbase + r16;
    int rA1 = rowbase + 16 + r16;
    rA0 = rA0 < N_NODES ? rA0 : N_NODES - 1;
    rA1 = rA1 < N_NODES ? rA1 : N_NODES - 1;
    const float* xp0 = x + (size_t)rA0 * IN_DIM + q * 8;
    const float* xp1 = x + (size_t)rA1 * IN_DIM + q * 8;

    // ---- prologue: load + pack the wave's ENTIRE A panel into registers
    uint4 Areg[2][8];
#pragma unroll
    for (int kc = 0; kc < 8; kc++) {
        const float4 a00 = *(const float4*)(xp0 + kc * 32);
        const float4 a01 = *(const float4*)(xp0 + kc * 32 + 4);
        const float4 a10 = *(const float4*)(xp1 + kc * 32);
        const float4 a11 = *(const float4*)(xp1 + kc * 32 + 4);
        Areg[0][kc].x = pack2(a00.x, a00.y); Areg[0][kc].y = pack2(a00.z, a00.w);
        Areg[0][kc].z = pack2(a01.x, a01.y); Areg[0][kc].w = pack2(a01.z, a01.w);
        Areg[1][kc].x = pack2(a10.x, a10.y); Areg[1][kc].y = pack2(a10.z, a10.w);
        Areg[1][kc].z = pack2(a11.x, a11.y); Areg[1][kc].w = pack2(a11.z, a11.w);
    }

    f32x4 acc[2][8];
#pragma unroll
    for (int c = 0; c < 8; c++) {
        acc[0][c] = (f32x4){0.f, 0.f, 0.f, 0.f};
        acc[1][c] = (f32x4){0.f, 0.f, 0.f, 0.f};
    }

    __syncthreads();   // B slab visible; the only barrier in the kernel

    // ---- K-loop: global-free, barrier-free, fully unrolled
#pragma unroll
    for (int kc = 0; kc < 8; kc++) {
        const bf16x8 af0 = *(const bf16x8*)&Areg[0][kc];
        const bf16x8 af1 = *(const bf16x8*)&Areg[1][kc];
#pragma unroll
        for (int c = 0; c < 8; c++) {
            const bf16x8 bf = *(const bf16x8*)&Bs[((c * 8 + kc) * 64 + lane) * 8];
            acc[0][c] = __builtin_amdgcn_mfma_f32_16x16x32_bf16(af0, bf, acc[0][c], 0, 0, 0);
            acc[1][c] = __builtin_amdgcn_mfma_f32_16x16x32_bf16(af1, bf, acc[1][c], 0, 0, 0);
        }
    }
#pragma unroll
    for (int mt = 0; mt < 2; mt++)
#pragma unroll
        for (int c = 0; c < 8; c++)
#pragma unroll
            for (int rr = 0; rr < 4; rr++) {
                const int row = rowbase + mt * 16 + q * 4 + rr;
                if (row < N_NODES)
                    Zb[(size_t)row * ZDIM + (cbase + c) * 16 + r16] = f2bf(acc[mt][c][rr]);
            }
}

// ---------------------------------------------------------------------------
// K3: fused logits + online segment-softmax + weighted accumulate.
// 16 lanes per node, 4 nodes per wave, 16 nodes per block (R5 form — best
// measured). Lane l16 owns channels 8*l16..8*l16+7 (l16<8: head0, else
// head1). Per edge: uint4 gather of Us[src] + Wh[src], 1-deep prefetch;
// 3 xor-shuffles; per-lane online (m,l); head-mean via final xor-8.
// ---------------------------------------------------------------------------
__global__ __launch_bounds__(256) void k_fused(const ushort* __restrict__ Zb,
                                               const float* __restrict__ avec,
                                               const int* __restrict__ src,
                                               const int* __restrict__ seg,
                                               float* __restrict__ out) {
    const int lane = threadIdx.x & 63;
    const int wv = threadIdx.x >> 6;
    const int g = lane >> 4, l16 = lane & 15;
    const int n = blockIdx.x * 16 + wv * 4 + g;
    if (n >= N_NODES) return;
    const int choff = 8 * l16;

    const float4 af0 = *(const float4*)(avec + choff);
    const float4 af1 = *(const float4*)(avec + choff + 4);
    const float a[8] = {af0.x, af0.y, af0.z, af0.w, af1.x, af1.y, af1.z, af1.w};

    const uint4 udv = *(const uint4*)(Zb + (size_t)n * ZDIM + 256 + choff);
    const float ud[8] = {bfl(udv.x), bfh(udv.x), bfl(udv.y), bfh(udv.y),
                         bfl(udv.z), bfh(udv.z), bfl(udv.w), bfh(udv.w)};

    const int e0 = seg[n], e1 = seg[n + 1];
    float m = -INFINITY, l = 0.f;
    float acc[8] = {0.f, 0.f, 0.f, 0.f, 0.f, 0.f, 0.f, 0.f};

    uint4 us = make_uint4(0, 0, 0, 0), wh = us;
    if (e0 < e1) {
        const int s = src[e0];
        us = *(const uint4*)(Zb + (size_t)s * ZDIM + 128 + choff);
        wh = *(const uint4*)(Zb + (size_t)s * ZDIM + choff);
    }
    for (int e = e0; e < e1; e++) {
        const uint4 cus = us, cwh = wh;
        if (e + 1 < e1) {                 // prefetch next edge during reduce
            const int sn = src[e + 1];
            us = *(const uint4*)(Zb + (size_t)sn * ZDIM + 128 + choff);
            wh = *(const uint4*)(Zb + (size_t)sn * ZDIM + choff);
        }
        float p;
        {
            float v0, v1, s0, s1;
            v0 = bfl(cus.x) + ud[0]; v1 = bfh(cus.x) + ud[1];
            s0 = fmaxf(v0, ALPHA_SLOPE * v0); s1 = fmaxf(v1, ALPHA_SLOPE * v1);
            p = s0 * a[0] + s1 * a[1];
            v0 = bfl(cus.y) + ud[2]; v1 = bfh(cus.y) + ud[3];
            s0 = fmaxf(v0, ALPHA_SLOPE * v0); s1 = fmaxf(v1, ALPHA_SLOPE * v1);
            p += s0 * a[2] + s1 * a[3];
            v0 = bfl(cus.z) + ud[4]; v1 = bfh(cus.z) + ud[5];
            s0 = fmaxf(v0, ALPHA_SLOPE * v0); s1 = fmaxf(v1, ALPHA_SLOPE * v1);
            p += s0 * a[4] + s1 * a[5];
            v0 = bfl(cus.w) + ud[6]; v1 = bfh(cus.w) + ud[7];
            s0 = fmaxf(v0, ALPHA_SLOPE * v0); s1 = fmaxf(v1, ALPHA_SLOPE * v1);
            p += s0 * a[6] + s1 * a[7];
        }
        p += __shfl_xor(p, 1, 64);
        p += __shfl_xor(p, 2, 64);
        p += __shfl_xor(p, 4, 64);        // lanes 0-7: head0 logit, 8-15: head1
        const float logit = p * (1.0f / TEMP);
        const float nm = fmaxf(m, logit);
        const float sc = __expf(m - nm);       // first iter: exp(-inf)=0
        const float wgt = __expf(logit - nm);
        l = l * sc + wgt;
        acc[0] = acc[0] * sc + wgt * bfl(cwh.x);
        acc[1] = acc[1] * sc + wgt * bfh(cwh.x);
        acc[2] = acc[2] * sc + wgt * bfl(cwh.y);
        acc[3] = acc[3] * sc + wgt * bfh(cwh.y);
        acc[4] = acc[4] * sc + wgt * bfl(cwh.z);
        acc[5] = acc[5] * sc + wgt * bfh(cwh.z);
        acc[6] = acc[6] * sc + wgt * bfl(cwh.w);
        acc[7] = acc[7] * sc + wgt * bfh(cwh.w);
        m = nm;
    }
    const float inv = 0.5f / (l + 1e-9f);      // ref 1/(sum+1e-9) + head-mean
#pragma unroll
    for (int j = 0; j < 8; j++) {
        const float v = acc[j] * inv;
        acc[j] = v + __shfl_xor(v, 8, 64);     // head0[c] + head1[c]
    }
    if (l16 < 8) {
        float4 o0 = make_float4(acc[0], acc[1], acc[2], acc[3]);
        float4 o1 = make_float4(acc[4], acc[5], acc[6], acc[7]);
        float* op = out + (size_t)n * 64 + choff;
        *(float4*)op = o0;
        *(float4*)(op + 4) = o1;
    }
}

// ---------------------------------------------------------------------------
extern "C" void kernel_launch(void* const* d_in, const int* in_sizes, int n_in,
                              void* d_out, int out_size, void* d_ws, size_t ws_size,
                              hipStream_t stream) {
    const float* x    = (const float*)d_in[0];
    const float* W    = (const float*)d_in[1];
    const float* Wa   = (const float*)d_in[2];
    const float* avec = (const float*)d_in[3];
    const int*   src  = (const int*)d_in[4];
    const int*   dst  = (const int*)d_in[5];
    float* out = (float*)d_out;

    ushort* Zb   = (ushort*)d_ws;                      // 19,200,000 bf16 = 38.4 MB
    ushort* Wctf = Zb + 19200000;                      // 98,304 bf16 (fragment order)
    int*    seg  = (int*)((char*)d_ws + 38596608);     // 50,001 ints

    const int seg_blocks = (N_NODES + 1 + 255) / 256;  // 196
    k_combine <<<ZDIM + seg_blocks, 256, 0, stream>>>(W, Wa, Wctf, dst, seg);
    k_gemm    <<<dim3(3, (N_NODES + 127) / 128), 256, 0, stream>>>(x, Wctf, Zb);
    k_fused   <<<(N_NODES + 15) / 16, 256, 0, stream>>>(Zb, avec, src, seg, out);
}

// Round 13
// 157.170 us; speedup vs baseline: 1.3268x; 1.0340x over previous
//
#include <hip/hip_runtime.h>
#include <hip/hip_bf16.h>
#include <math.h>

#define N_NODES 50000
#define N_EDGES 400000
#define IN_DIM 256
#define OUT_DIM 64
#define HEADS 2
#define ATTN_HIDDEN 64
#define ALPHA_SLOPE 0.2f
#define TEMP 0.55f
#define NHF 128   // HEADS*OUT_DIM
#define ZDIM 384  // Wh(128) | Us(128) | Ud(128)

typedef __bf16 bf16x8 __attribute__((ext_vector_type(8)));
typedef float f32x4 __attribute__((ext_vector_type(4)));

__device__ __forceinline__ ushort f2bf(float f) {
    unsigned u = __float_as_uint(f);
    u = (u + 0x7fffu + ((u >> 16) & 1u)) >> 16;
    return (ushort)u;
}
__device__ __forceinline__ unsigned pack2(float a, float b) {
    return (unsigned)f2bf(a) | ((unsigned)f2bf(b) << 16);
}
__device__ __forceinline__ float bfl(unsigned u) { return __uint_as_float(u << 16); }
__device__ __forceinline__ float bfh(unsigned u) { return __uint_as_float(u & 0xffff0000u); }

// ---------------------------------------------------------------------------
// K1: build Wctf (combined weights, MFMA B-fragment order) + seg[] (segment
// starts) in one launch. Fragment position for (n,k): c=n>>4, r16=n&15,
// kc=k>>5, q=(k>>3)&3, j=k&7 -> pos = ((c*8+kc)*64 + q*16 + r16)*8 + j.
// Each 8-c-tile group (128 cols) is a contiguous 64 KB slab.
// ---------------------------------------------------------------------------
__global__ __launch_bounds__(256) void k_combine(const float* __restrict__ W,
                                                 const float* __restrict__ Wa,
                                                 ushort* __restrict__ Wctf,
                                                 const int* __restrict__ dst,
                                                 int* __restrict__ seg) {
    __shared__ float col[64];
    const int b = blockIdx.x;
    const int t = threadIdx.x;
    if (b >= ZDIM) {   // segstart path
        int n = (b - ZDIM) * 256 + t;
        if (n > N_NODES) return;
        int lo = 0, hi = N_EDGES;
        while (lo < hi) {
            int mid = (lo + hi) >> 1;
            if (dst[mid] < n) lo = mid + 1; else hi = mid;
        }
        seg[n] = lo;
        return;
    }
    const int n = b;      // output column 0..383
    const int k = t;      // input dim 0..255
    const int c = n >> 4, r16 = n & 15;
    const int kc = k >> 5, q = (k >> 3) & 3, j = k & 7;
    const size_t pos = (size_t)(((c * 8 + kc) * 64 + q * 16 + r16)) * 8 + j;

    float val;
    if (n < 128) {
        val = W[(size_t)k * NHF + n];
    } else {
        const int part = (n - 128) >> 7;       // 0 = src-half, 1 = dst-half
        const int idx = (n - 128) & 127;
        const int h = idx >> 6;
        const int cc = idx & 63;
        const int fb = part ? 64 : 0;
        if (t < 64) col[t] = Wa[(size_t)h * 8192 + (size_t)(fb + t) * 64 + cc];
        __syncthreads();
        const float* wr = W + (size_t)k * NHF + h * 64;
        float acc = 0.f;
#pragma unroll
        for (int f = 0; f < 64; f++) acc += wr[f] * col[f];
        val = acc;
    }
    Wctf[pos] = f2bf(val);
}

// ---------------------------------------------------------------------------
// K2: Z[50000,384] = x @ Wcomb. Grid = 782 row-blocks; block = 4 waves x 16
// rows = 64 rows. A panel (8 uint4/lane after bf16 pack) loaded ONCE in the
// prologue — x is fetched exactly once from HBM. The block then loops over
// the 3 column-slabs: stage slab (64 KB = 4096 uint4, coalesced ->
// lane-linear ds_write_b128), barrier, barrier-free K-loop (64 ds_read_b128
// + 64 MFMA per wave), barrier, stage next. Epilogue stores for slab s are
// issued between the two barriers so they overlap slab s+1's staging.
// A frag: A[m=lane&15][k=(lane>>4)*8+j]; D: row=(lane>>4)*4+rr, col=lane&15.
// ---------------------------------------------------------------------------
__global__ __launch_bounds__(256, 2) void k_gemm(const float* __restrict__ x,
                                                 const ushort* __restrict__ Wctf,
                                                 ushort* __restrict__ Zb) {
    __shared__ __align__(16) ushort Bs[32768];   // 64 KB, single buffer
    const int t = threadIdx.x;
    const int w = t >> 6, lane = t & 63;
    const int q = lane >> 4, r16 = lane & 15;
    const int rowbase = blockIdx.x * 64 + w * 16;    // wave's 16 rows

    // ---- stage slab 0 (slab = 4096 uint4 = 64 KB)
    {
        const uint4* gs = (const uint4*)Wctf;
        uint4* ls = (uint4*)Bs;
#pragma unroll
        for (int i = 0; i < 16; i++) ls[i * 256 + t] = gs[i * 256 + t];
    }

    // ---- prologue: load + pack the wave's ENTIRE A panel (read x ONCE)
    int rA = rowbase + r16;
    rA = rA < N_NODES ? rA : N_NODES - 1;
    const float* xp = x + (size_t)rA * IN_DIM + q * 8;
    uint4 Areg[8];
#pragma unroll
    for (int kc = 0; kc < 8; kc++) {
        const float4 a0 = *(const float4*)(xp + kc * 32);
        const float4 a1 = *(const float4*)(xp + kc * 32 + 4);
        Areg[kc].x = pack2(a0.x, a0.y); Areg[kc].y = pack2(a0.z, a0.w);
        Areg[kc].z = pack2(a1.x, a1.y); Areg[kc].w = pack2(a1.z, a1.w);
    }

    __syncthreads();   // slab 0 visible

#pragma unroll 1
    for (int s = 0; s < 3; s++) {
        f32x4 acc[8];
#pragma unroll
        for (int c = 0; c < 8; c++) acc[c] = (f32x4){0.f, 0.f, 0.f, 0.f};

        // K-loop: global-free, barrier-free, fully unrolled
#pragma unroll
        for (int kc = 0; kc < 8; kc++) {
            const bf16x8 af = *(const bf16x8*)&Areg[kc];
#pragma unroll
            for (int c = 0; c < 8; c++) {
                const bf16x8 bf = *(const bf16x8*)&Bs[((c * 8 + kc) * 64 + lane) * 8];
                acc[c] = __builtin_amdgcn_mfma_f32_16x16x32_bf16(af, bf, acc[c], 0, 0, 0);
            }
        }

        if (s < 2) {
            __syncthreads();   // everyone done reading slab s
            // stage slab s+1 (4096 uint4 per slab!) — epilogue overlaps this
            const uint4* gs = (const uint4*)Wctf + (size_t)(s + 1) * 4096;
            uint4* ls = (uint4*)Bs;
#pragma unroll
            for (int i = 0; i < 16; i++) ls[i * 256 + t] = gs[i * 256 + t];
        }

        // epilogue for slab s
#pragma unroll
        for (int c = 0; c < 8; c++)
#pragma unroll
            for (int rr = 0; rr < 4; rr++) {
                const int row = rowbase + q * 4 + rr;
                if (row < N_NODES)
                    Zb[(size_t)row * ZDIM + (s * 8 + c) * 16 + r16] = f2bf(acc[c][rr]);
            }

        if (s < 2) __syncthreads();   // slab s+1 visible
    }
}

// ---------------------------------------------------------------------------
// K3: fused logits + online segment-softmax + weighted accumulate.
// 16 lanes per node, 4 nodes per wave, 16 nodes per block (best measured
// form). Lane l16 owns channels 8*l16..8*l16+7 (l16<8: head0, else head1).
// Per edge: uint4 gather of Us[src] + Wh[src], 1-deep prefetch; 3
// xor-shuffles; per-lane online (m,l); head-mean via final xor-8.
// ---------------------------------------------------------------------------
__global__ __launch_bounds__(256) void k_fused(const ushort* __restrict__ Zb,
                                               const float* __restrict__ avec,
                                               const int* __restrict__ src,
                                               const int* __restrict__ seg,
                                               float* __restrict__ out) {
    const int lane = threadIdx.x & 63;
    const int wv = threadIdx.x >> 6;
    const int g = lane >> 4, l16 = lane & 15;
    const int n = blockIdx.x * 16 + wv * 4 + g;
    if (n >= N_NODES) return;
    const int choff = 8 * l16;

    const float4 af0 = *(const float4*)(avec + choff);
    const float4 af1 = *(const float4*)(avec + choff + 4);
    const float a[8] = {af0.x, af0.y, af0.z, af0.w, af1.x, af1.y, af1.z, af1.w};

    const uint4 udv = *(const uint4*)(Zb + (size_t)n * ZDIM + 256 + choff);
    const float ud[8] = {bfl(udv.x), bfh(udv.x), bfl(udv.y), bfh(udv.y),
                         bfl(udv.z), bfh(udv.z), bfl(udv.w), bfh(udv.w)};

    const int e0 = seg[n], e1 = seg[n + 1];
    float m = -INFINITY, l = 0.f;
    float acc[8] = {0.f, 0.f, 0.f, 0.f, 0.f, 0.f, 0.f, 0.f};

    uint4 us = make_uint4(0, 0, 0, 0), wh = us;
    if (e0 < e1) {
        const int s = src[e0];
        us = *(const uint4*)(Zb + (size_t)s * ZDIM + 128 + choff);
        wh = *(const uint4*)(Zb + (size_t)s * ZDIM + choff);
    }
    for (int e = e0; e < e1; e++) {
        const uint4 cus = us, cwh = wh;
        if (e + 1 < e1) {                 // prefetch next edge during reduce
            const int sn = src[e + 1];
            us = *(const uint4*)(Zb + (size_t)sn * ZDIM + 128 + choff);
            wh = *(const uint4*)(Zb + (size_t)sn * ZDIM + choff);
        }
        float p;
        {
            float v0, v1, s0, s1;
            v0 = bfl(cus.x) + ud[0]; v1 = bfh(cus.x) + ud[1];
            s0 = fmaxf(v0, ALPHA_SLOPE * v0); s1 = fmaxf(v1, ALPHA_SLOPE * v1);
            p = s0 * a[0] + s1 * a[1];
            v0 = bfl(cus.y) + ud[2]; v1 = bfh(cus.y) + ud[3];
            s0 = fmaxf(v0, ALPHA_SLOPE * v0); s1 = fmaxf(v1, ALPHA_SLOPE * v1);
            p += s0 * a[2] + s1 * a[3];
            v0 = bfl(cus.z) + ud[4]; v1 = bfh(cus.z) + ud[5];
            s0 = fmaxf(v0, ALPHA_SLOPE * v0); s1 = fmaxf(v1, ALPHA_SLOPE * v1);
            p += s0 * a[4] + s1 * a[5];
            v0 = bfl(cus.w) + ud[6]; v1 = bfh(cus.w) + ud[7];
            s0 = fmaxf(v0, ALPHA_SLOPE * v0); s1 = fmaxf(v1, ALPHA_SLOPE * v1);
            p += s0 * a[6] + s1 * a[7];
        }
        p += __shfl_xor(p, 1, 64);
        p += __shfl_xor(p, 2, 64);
        p += __shfl_xor(p, 4, 64);        // lanes 0-7: head0 logit, 8-15: head1
        const float logit = p * (1.0f / TEMP);
        const float nm = fmaxf(m, logit);
        const float sc = __expf(m - nm);       // first iter: exp(-inf)=0
        const float wgt = __expf(logit - nm);
        l = l * sc + wgt;
        acc[0] = acc[0] * sc + wgt * bfl(cwh.x);
        acc[1] = acc[1] * sc + wgt * bfh(cwh.x);
        acc[2] = acc[2] * sc + wgt * bfl(cwh.y);
        acc[3] = acc[3] * sc + wgt * bfh(cwh.y);
        acc[4] = acc[4] * sc + wgt * bfl(cwh.z);
        acc[5] = acc[5] * sc + wgt * bfh(cwh.z);
        acc[6] = acc[6] * sc + wgt * bfl(cwh.w);
        acc[7] = acc[7] * sc + wgt * bfh(cwh.w);
        m = nm;
    }
    const float inv = 0.5f / (l + 1e-9f);      // ref 1/(sum+1e-9) + head-mean
#pragma unroll
    for (int j = 0; j < 8; j++) {
        const float v = acc[j] * inv;
        acc[j] = v + __shfl_xor(v, 8, 64);     // head0[c] + head1[c]
    }
    if (l16 < 8) {
        float4 o0 = make_float4(acc[0], acc[1], acc[2], acc[3]);
        float4 o1 = make_float4(acc[4], acc[5], acc[6], acc[7]);
        float* op = out + (size_t)n * 64 + choff;
        *(float4*)op = o0;
        *(float4*)(op + 4) = o1;
    }
}

// ---------------------------------------------------------------------------
extern "C" void kernel_launch(void* const* d_in, const int* in_sizes, int n_in,
                              void* d_out, int out_size, void* d_ws, size_t ws_size,
                              hipStream_t stream) {
    const float* x    = (const float*)d_in[0];
    const float* W    = (const float*)d_in[1];
    const float* Wa   = (const float*)d_in[2];
    const float* avec = (const float*)d_in[3];
    const int*   src  = (const int*)d_in[4];
    const int*   dst  = (const int*)d_in[5];
    float* out = (float*)d_out;

    ushort* Zb   = (ushort*)d_ws;                      // 19,200,000 bf16 = 38.4 MB
    ushort* Wctf = Zb + 19200000;                      // 98,304 bf16 (fragment order)
    int*    seg  = (int*)((char*)d_ws + 38596608);     // 50,001 ints

    const int seg_blocks = (N_NODES + 1 + 255) / 256;  // 196
    k_combine <<<ZDIM + seg_blocks, 256, 0, stream>>>(W, Wa, Wctf, dst, seg);
    k_gemm    <<<(N_NODES + 63) / 64, 256, 0, stream>>>(x, Wctf, Zb);
    k_fused   <<<(N_NODES + 15) / 16, 256, 0, stream>>>(Zb, avec, src, seg, out);
}